// Round 3
// baseline (211.601 us; speedup 1.0000x reference)
//
#include <hip/hip_runtime.h>

typedef __attribute__((ext_vector_type(4))) float          f32x4;
typedef __attribute__((ext_vector_type(8))) short          bf16x8;
typedef __attribute__((ext_vector_type(4))) unsigned short u16x4;
typedef __attribute__((ext_vector_type(8))) unsigned short u16x8;

__device__ __forceinline__ unsigned short f2bf(float f) {
  union { float f; unsigned u; } v; v.f = f;
  unsigned r = v.u + 0x7fffu + ((v.u >> 16) & 1u);   // RNE
  return (unsigned short)(r >> 16);
}

#define S_  128
#define I_  256
#define D_  64
#define P_  32
#define DO_ 128

// ---------------------------------------------------------------------------
// K1: LayerNorm + left/right projections.
// Outputs plain transposed layouts:
//   LtT[ip][s] = left[s][i=ip>>5][p=ip&31]   (8192 x 128 bf16)
//   RtT[jq][s] = right[s][j=jq>>5][q=jq&31]  (8192 x 128 bf16)
// Three __syncthreads-separated phases; no intra-wave LDS tricks.
// ---------------------------------------------------------------------------
__global__ __launch_bounds__(256) void ln_proj(
    const float* __restrict__ M,  const float* __restrict__ gamma,
    const float* __restrict__ beta,
    const float* __restrict__ Wa, const float* __restrict__ ba,
    const float* __restrict__ Wb, const float* __restrict__ bb,
    unsigned short* __restrict__ LtT, unsigned short* __restrict__ RtT)
{
  __shared__ __align__(16) float mnAll[128 * 68];  // [s][d], stride 68 (16B-aligned rows)
  __shared__ __align__(16) float lsm[128 * 33];    // [s][p]
  __shared__ __align__(16) float rsm[128 * 33];    // [s][q]

  const int tid  = threadIdx.x;
  const int lane = tid & 63;
  const int w    = tid >> 6;      // wave 0..3, owns s in [w*32, w*32+32)
  const int i    = blockIdx.x;    // residue 0..255

  // ---- Phase A: LayerNorm (lane = feature d) ----
  const float g  = gamma[lane];
  const float be = beta[lane];
  for (int u = 0; u < 32; ++u) {
    int s = w * 32 + u;
    float x = M[(s * I_ + i) * D_ + lane];
    float s1 = x, s2 = x * x;
    #pragma unroll
    for (int m = 1; m < 64; m <<= 1) {
      s1 += __shfl_xor(s1, m, 64);
      s2 += __shfl_xor(s2, m, 64);
    }
    float mean = s1 * (1.0f / 64.0f);
    float var  = s2 * (1.0f / 64.0f) - mean * mean;
    float xn   = (x - mean) * rsqrtf(var + 1e-5f) * g + be;
    mnAll[s * 68 + lane] = xn;
  }
  __syncthreads();

  // ---- Phase B: projections (lane = projection unit: p for left, q for right) ----
  {
    const int p    = lane & 31;
    const int side = lane >> 5;   // 0 = left (Wa), 1 = right (Wb)
    const float* wrow = (side ? Wb : Wa) + p * D_;
    const float  bias = side ? bb[p] : ba[p];
    f32x4 wv[16];
    #pragma unroll
    for (int c = 0; c < 16; ++c) wv[c] = *(const f32x4*)(wrow + c * 4);
    float* dst = side ? rsm : lsm;
    for (int u = 0; u < 32; ++u) {
      int s = w * 32 + u;
      float acc = bias;
      #pragma unroll
      for (int c = 0; c < 16; ++c) {
        f32x4 m4 = *(const f32x4*)(&mnAll[s * 68 + c * 4]);  // 272B row stride: 16B aligned
        acc += m4.x * wv[c].x + m4.y * wv[c].y + m4.z * wv[c].z + m4.w * wv[c].w;
      }
      dst[s * 33 + p] = acc;
    }
  }
  __syncthreads();

  // ---- Phase C: transpose write-out, bf16, coalesced u16x8 stores ----
  // 1024 items: arr(2) x row p(32) x chunk c(16); chunk = 8 consecutive s.
  for (int it = 0; it < 4; ++it) {
    int idx = it * 256 + tid;
    int arr = idx >> 9;
    int rem = idx & 511;
    int p   = rem >> 4;
    int c   = rem & 15;
    int s0  = c * 8;
    const float* src = arr ? rsm : lsm;
    unsigned short* dstg = (arr ? RtT : LtT) + (i * 32 + p) * S_ + s0;
    u16x8 v;
    #pragma unroll
    for (int k = 0; k < 8; ++k) v[k] = f2bf(src[(s0 + k) * 33 + p]);
    *(u16x8*)dstg = v;
  }
}

// ---------------------------------------------------------------------------
// K2: Wo -> WoP[o][k'] with k' = q*32 + p holding Wo[o][p*32+q]  (128 x 1024 bf16)
// ---------------------------------------------------------------------------
__global__ __launch_bounds__(256) void wo_pack(
    const float* __restrict__ Wo, unsigned short* __restrict__ WoP)
{
  int f  = blockIdx.x * 256 + threadIdx.x;   // 512 blocks -> 131072
  int o  = f >> 10;
  int kp = f & 1023;        // k' = q*32 + p
  int q  = kp >> 5;
  int p  = kp & 31;
  WoP[f] = f2bf(Wo[o * 1024 + p * 32 + q]);
}

// ---------------------------------------------------------------------------
// K3: fused  O = Lt^T * Rt (K=S=128)  ->  LDS bf16 (padded stride)  ->
//           Z = O * Wo^T + bo  (K=1024, N=128)
// Block = 8 waves (512 thr): 256x256 O tile (8x8 residue pairs), 64x128 Z.
// ---------------------------------------------------------------------------
__global__ __launch_bounds__(512) void fused_gemm(
    const unsigned short* __restrict__ LtT,
    const unsigned short* __restrict__ RtT,
    const unsigned short* __restrict__ WoP,
    const float* __restrict__ bo,
    float* __restrict__ Z)
{
  // Osh[pair][k'], row stride 1048 ushorts (2096 B). 64*1048*2 = 134144 B.
  // Bank map of GEMM2 reads: (12*l15 + 4*l4) mod 32 -> exactly uniform, conflict-free.
  __shared__ __align__(16) unsigned short Osh[64 * 1048];

  const int tid  = threadIdx.x;
  const int lane = tid & 63;
  const int wid  = tid >> 6;
  const int l15  = lane & 15;
  const int l4   = lane >> 4;
  const int ti   = blockIdx.x >> 5;   // 0..31
  const int tj   = blockIdx.x & 31;   // 0..31

  // ---------------- GEMM1 ----------------
  {
    const int wr = wid >> 2;   // 0..1 : ip rows [wr*128, +128)
    const int wc = wid & 3;    // 0..3 : jq cols [wc*64, +64)
    f32x4 acc[8][4];
    #pragma unroll
    for (int a = 0; a < 8; ++a)
      #pragma unroll
      for (int b = 0; b < 4; ++b) { f32x4 z = {0.f, 0.f, 0.f, 0.f}; acc[a][b] = z; }

    #pragma unroll
    for (int kk = 0; kk < 4; ++kk) {
      bf16x8 af[8], bfr[4];
      #pragma unroll
      for (int rt = 0; rt < 8; ++rt) {
        int ip = ((ti * 16 + wr * 8 + rt) * 16 + l15);      // global left row
        af[rt] = *(const bf16x8*)(LtT + ip * S_ + kk * 32 + l4 * 8);
      }
      #pragma unroll
      for (int ct = 0; ct < 4; ++ct) {
        int jq = ((tj * 16 + wc * 4 + ct) * 16 + l15);      // global right row
        bfr[ct] = *(const bf16x8*)(RtT + jq * S_ + kk * 32 + l4 * 8);
      }
      #pragma unroll
      for (int rt = 0; rt < 8; ++rt)
        #pragma unroll
        for (int ct = 0; ct < 4; ++ct)
          acc[rt][ct] = __builtin_amdgcn_mfma_f32_16x16x32_bf16(
              af[rt], bfr[ct], acc[rt][ct], 0, 0, 0);
    }

    // O -> LDS bf16. D-layout: col(jq)=l15, row(ip)=l4*4+reg.
    #pragma unroll
    for (int rt = 0; rt < 8; ++rt) {
      int ip_base = wr * 128 + rt * 16 + l4 * 4;    // local ip, +r in reg index
      int li = ip_base >> 5;
      int p0 = ip_base & 31;                        // multiple of 4
      #pragma unroll
      for (int ct = 0; ct < 4; ++ct) {
        int jq = wc * 64 + ct * 16 + l15;           // local jq
        int lj = jq >> 5, q = jq & 31;
        u16x4 v;
        v.x = f2bf(acc[rt][ct][0]);
        v.y = f2bf(acc[rt][ct][1]);
        v.z = f2bf(acc[rt][ct][2]);
        v.w = f2bf(acc[rt][ct][3]);
        *(u16x4*)(Osh + (li * 8 + lj) * 1048 + q * 32 + p0) = v;  // 8B aligned
      }
    }
  }
  __syncthreads();

  // ---------------- GEMM2 ----------------
  {
    const int wm = wid >> 2;   // pair rows [wm*32, +32)
    const int wn = wid & 3;    // o cols   [wn*32, +32)
    f32x4 zacc[2][2];
    #pragma unroll
    for (int a = 0; a < 2; ++a)
      #pragma unroll
      for (int b = 0; b < 2; ++b) { f32x4 z = {0.f, 0.f, 0.f, 0.f}; zacc[a][b] = z; }

    for (int kk2 = 0; kk2 < 32; ++kk2) {
      bf16x8 wfr[2];
      #pragma unroll
      for (int ctb = 0; ctb < 2; ++ctb) {
        int o = (wn * 2 + ctb) * 16 + l15;
        wfr[ctb] = *(const bf16x8*)(WoP + o * 1024 + kk2 * 32 + l4 * 8);
      }
      #pragma unroll
      for (int mt = 0; mt < 2; ++mt) {
        int row = wm * 32 + mt * 16 + l15;
        bf16x8 afr = *(const bf16x8*)(Osh + row * 1048 + kk2 * 32 + l4 * 8);
        #pragma unroll
        for (int ctb = 0; ctb < 2; ++ctb)
          zacc[mt][ctb] = __builtin_amdgcn_mfma_f32_16x16x32_bf16(
              afr, wfr[ctb], zacc[mt][ctb], 0, 0, 0);
      }
    }

    float bov[2];
    #pragma unroll
    for (int ctb = 0; ctb < 2; ++ctb) bov[ctb] = bo[(wn * 2 + ctb) * 16 + l15];

    #pragma unroll
    for (int mt = 0; mt < 2; ++mt) {
      #pragma unroll
      for (int r = 0; r < 4; ++r) {
        int pair = wm * 32 + mt * 16 + l4 * 4 + r;
        int li = pair >> 3, lj = pair & 7;
        float* zrow = Z + ((ti * 8 + li) * I_ + (tj * 8 + lj)) * DO_;
        #pragma unroll
        for (int ctb = 0; ctb < 2; ++ctb)
          zrow[(wn * 2 + ctb) * 16 + l15] = zacc[mt][ctb][r] + bov[ctb];
      }
    }
  }
}

// ---------------------------------------------------------------------------
extern "C" void kernel_launch(void* const* d_in, const int* in_sizes, int n_in,
                              void* d_out, int out_size, void* d_ws, size_t ws_size,
                              hipStream_t stream) {
  const float* M     = (const float*)d_in[0];
  const float* gamma = (const float*)d_in[1];
  const float* beta  = (const float*)d_in[2];
  const float* Wa    = (const float*)d_in[3];
  const float* ba    = (const float*)d_in[4];
  const float* Wb    = (const float*)d_in[5];
  const float* bb    = (const float*)d_in[6];
  const float* Wo    = (const float*)d_in[7];
  const float* bo    = (const float*)d_in[8];
  float* Z = (float*)d_out;

  // workspace (ushort elements): LtT 1,048,576 | RtT 1,048,576 | WoP 131,072
  unsigned short* LtT = (unsigned short*)d_ws;
  unsigned short* RtT = LtT + 1048576;
  unsigned short* WoP = RtT + 1048576;

  ln_proj<<<256, 256, 0, stream>>>(M, gamma, beta, Wa, ba, Wb, bb, LtT, RtT);
  wo_pack<<<512, 256, 0, stream>>>(Wo, WoP);
  fused_gemm<<<1024, 512, 0, stream>>>(LtT, RtT, WoP, bo, Z);
}